// Round 6
// baseline (593.993 us; speedup 1.0000x reference)
//
#include <hip/hip_runtime.h>
#include <math.h>

// LiteMLA bf16/MFMA pipeline. 2 chunks x 8 batches.
// K0 k_cvt_w : wq, wp fp32 -> bf16 (once)
// K1 k_tr_x  : x[c][n] fp32 -> xb_t[n][c] bf16
// K2 k_qkv_mm: qkv GEMM via mfma_f32_16x16x32_bf16, no-LDS direct frag loads
// K3 k_dwpw  : fused depthwise 5x5 + grouped pointwise, bf16 io, fp32 math
//              v3: marching-y blocks (768 total, 3/CU co-resident), 8-row
//              rotating register window, rows loaded once, weights once/block
// K4 k_vk   : partial vk[17][16] per (h,bb,ns) -> ws fp32   (2048 blocks)
// K5 k_att2 : reduce partials + pass2, writes att_t[n][512] (2048 blocks)
// K6 k_proj_mm: proj GEMM + BN affine, fp32 out

#define NBC 8

typedef unsigned short u16;
typedef __attribute__((ext_vector_type(8))) short short8v;
typedef __attribute__((ext_vector_type(8))) unsigned short us8;
typedef __attribute__((ext_vector_type(4))) float f32x4;

__device__ __forceinline__ u16 f2bf(float f) {
    union { float f; unsigned u; } v; v.f = f;
    unsigned r = v.u + 0x7fffu + ((v.u >> 16) & 1u);
    return (u16)(r >> 16);
}
__device__ __forceinline__ float bf2f(u16 u) {
    union { unsigned u; float f; } v; v.u = ((unsigned)u) << 16;
    return v.f;
}
__device__ __forceinline__ float4 ld4bf(const u16* p) {
    ushort4 u = *(const ushort4*)p;
    return make_float4(bf2f(u.x), bf2f(u.y), bf2f(u.z), bf2f(u.w));
}

// ---------------- K0: weight conversion ----------------
__global__ __launch_bounds__(256) void k_cvt_w(const float* __restrict__ wq,
                                               const float* __restrict__ wp,
                                               u16* __restrict__ wqb, u16* __restrict__ wpb) {
    int i = blockIdx.x * 256 + threadIdx.x;
    if (i < 768 * 256) wqb[i] = f2bf(wq[i]);
    if (i < 256 * 512) wpb[i] = f2bf(wp[i]);
}

// ---------------- K1: transpose x -> xb_t bf16 ----------------
__global__ __launch_bounds__(256) void k_tr_x(const float* __restrict__ x,
                                              u16* __restrict__ xbt, int b0) {
    __shared__ u16 t[64][72];
    const int nt = blockIdx.x, ct = blockIdx.y, bb = blockIdx.z;
    const int tid = threadIdx.x;
    const float* xp = x + ((size_t)(b0 + bb) * 256 + ct * 64) * 4096 + nt * 64;
    {
        int cr = tid >> 2, q = tid & 3;
#pragma unroll
        for (int j = 0; j < 4; j++) {
            float4 v = *(const float4*)&xp[(size_t)cr * 4096 + q * 16 + j * 4];
            ushort4 o;
            o.x = f2bf(v.x); o.y = f2bf(v.y); o.z = f2bf(v.z); o.w = f2bf(v.w);
            *(ushort4*)&t[cr][q * 16 + j * 4] = o;
        }
    }
    __syncthreads();
    {
        int nr = tid >> 2, co = (tid & 3) * 16;
        u16* op = xbt + ((size_t)bb * 4096 + nt * 64 + nr) * 256 + ct * 64 + co;
        us8 o0, o1;
#pragma unroll
        for (int j = 0; j < 8; j++) { o0[j] = t[co + j][nr]; o1[j] = t[co + 8 + j][nr]; }
        *(us8*)op = o0;
        *(us8*)(op + 8) = o1;
    }
}

// ---------------- K2: qkv GEMM (768x256 @ 256xN) ----------------
__global__ __launch_bounds__(256) void k_qkv_mm(const u16* __restrict__ xbt,
                                                const u16* __restrict__ wqb,
                                                u16* __restrict__ qkvb) {
    const int bid = blockIdx.x;
    const int mt = bid % 6, nt = bid / 6;
    const int m0 = mt * 128;
    const int cg = nt * 128;
    const int bb = cg >> 12, p0 = cg & 4095;
    const int tid = threadIdx.x, lane = tid & 63, w = tid >> 6;
    const int wm = w >> 1, wn = w & 1;
    const u16* aptr = xbt + ((size_t)bb * 4096 + p0 + wn * 64 + (lane & 15)) * 256 + (lane >> 4) * 8;
    const u16* bptr = wqb + (size_t)(m0 + wm * 64 + (lane & 15)) * 256 + (lane >> 4) * 8;

    f32x4 acc[4][4] = {};
#pragma unroll
    for (int ks = 0; ks < 8; ks++) {
        short8v af[4], bf[4];
#pragma unroll
        for (int i = 0; i < 4; i++) {
            af[i] = *(const short8v*)(aptr + (size_t)i * 16 * 256 + ks * 32);
            bf[i] = *(const short8v*)(bptr + (size_t)i * 16 * 256 + ks * 32);
        }
#pragma unroll
        for (int nf = 0; nf < 4; nf++)
#pragma unroll
            for (int mf = 0; mf < 4; mf++)
                acc[nf][mf] = __builtin_amdgcn_mfma_f32_16x16x32_bf16(af[nf], bf[mf], acc[nf][mf], 0, 0, 0);
    }
    const int mbase = m0 + wm * 64 + (lane & 15);
    const int nbase = p0 + wn * 64 + (lane >> 4) * 4;
#pragma unroll
    for (int nf = 0; nf < 4; nf++)
#pragma unroll
        for (int mf = 0; mf < 4; mf++) {
            int c = mbase + mf * 16;
            int nn = nbase + nf * 16;
            ushort4 o;
            o.x = f2bf(acc[nf][mf][0]);
            o.y = f2bf(acc[nf][mf][1]);
            o.z = f2bf(acc[nf][mf][2]);
            o.w = f2bf(acc[nf][mf][3]);
            *(ushort4*)(qkvb + ((size_t)bb * 768 + c) * 4096 + nn) = o;
        }
}

// ---------------- K3: fused depthwise 5x5 + grouped pointwise (v3: marching) ----------------
__global__ __launch_bounds__(256, 3) void k_dwpw(const u16* __restrict__ qkvb,
                                                 const float* __restrict__ wdw,
                                                 const float* __restrict__ wpw,
                                                 u16* __restrict__ aggb) {
    // grid: (ys 2, g 48, bb NBC) = 768 blocks; each marches 32 rows in 8 steps of 4
    __shared__ float dwt[16 * 4 * 68];  // [ic][ry][x], row stride 68
    const int tid = threadIdx.x;
    const int ys = blockIdx.x, g = blockIdx.y, bb = blockIdx.z;
    const int cl = tid >> 4, xq = tid & 15;
    const int c = g * 16 + cl;
    const int x0 = xq * 4;
    const int ybase = ys * 32;
    const u16* in = qkvb + ((size_t)bb * 768 + c) * 4096;
    u16* outp0 = aggb + ((size_t)bb * 768 + c) * 4096;  // oc == cl in pw phase

    float w[5][5];
#pragma unroll
    for (int dy = 0; dy < 5; dy++)
#pragma unroll
        for (int dx = 0; dx < 5; dx++) w[dy][dx] = wdw[c * 25 + dy * 5 + dx];
    float wv[16];
#pragma unroll
    for (int ic = 0; ic < 16; ic++) wv[ic] = wpw[(size_t)c * 16 + ic];

    float rows[8][8];  // rotating window; row yy lives in slot (yy+2)&7 (ybase%8==0)

#define LOADROW(YY, SLOT)                                                     \
    {                                                                         \
        int yy_ = (YY);                                                       \
        if (yy_ < 0 || yy_ > 63) {                                            \
            _Pragma("unroll") for (int j_ = 0; j_ < 8; j_++) rows[SLOT][j_] = 0.f; \
        } else {                                                              \
            const u16* rp_ = in + yy_ * 64;                                   \
            float4 v0_ = (x0 >= 4) ? ld4bf(rp_ + x0 - 4) : make_float4(0, 0, 0, 0); \
            float4 v1_ = ld4bf(rp_ + x0);                                     \
            float4 v2_ = (x0 + 4 < 64) ? ld4bf(rp_ + x0 + 4) : make_float4(0, 0, 0, 0); \
            rows[SLOT][0] = v0_.z; rows[SLOT][1] = v0_.w;                     \
            rows[SLOT][2] = v1_.x; rows[SLOT][3] = v1_.y;                     \
            rows[SLOT][4] = v1_.z; rows[SLOT][5] = v1_.w;                     \
            rows[SLOT][6] = v2_.x; rows[SLOT][7] = v2_.y;                     \
        }                                                                     \
    }

    // init: rows ybase-2 .. ybase+5 -> slots 0..7
#pragma unroll
    for (int i = 0; i < 8; i++) LOADROW(ybase - 2 + i, i)

#pragma unroll
    for (int s = 0; s < 8; s++) {
        // ---- depthwise: output rows ybase+4s .. +3 from slots (4s+ry+dy)&7 ----
#pragma unroll
        for (int ry = 0; ry < 4; ry++) {
            float o0 = 0.f, o1 = 0.f, o2 = 0.f, o3 = 0.f;
#pragma unroll
            for (int dy = 0; dy < 5; dy++) {
                const float* rr = rows[(4 * s + ry + dy) & 7];
#pragma unroll
                for (int dx = 0; dx < 5; dx++) {
                    float wvv = w[dy][dx];
                    o0 += rr[0 + dx] * wvv;
                    o1 += rr[1 + dx] * wvv;
                    o2 += rr[2 + dx] * wvv;
                    o3 += rr[3 + dx] * wvv;
                }
            }
            float4 ov = make_float4(o0, o1, o2, o3);
            *(float4*)&dwt[(cl * 4 + ry) * 68 + x0] = ov;
        }
        // ---- prefetch next 4 rows into the 4 just-freed slots ----
        if (s < 7) {
#pragma unroll
            for (int i = 0; i < 4; i++) LOADROW(ybase + 4 * s + 6 + i, (4 * s + i) & 7)
        }
        __syncthreads();
        // ---- grouped pointwise: thread = (oc=cl, 4px) ----
        {
            float acc[4][4];
#pragma unroll
            for (int j = 0; j < 4; j++)
#pragma unroll
                for (int p = 0; p < 4; p++) acc[j][p] = 0.f;
#pragma unroll
            for (int ic = 0; ic < 16; ic++) {
                float wvv = wv[ic];
#pragma unroll
                for (int j = 0; j < 4; j++) {
                    float4 f = *(const float4*)&dwt[(ic * 4 + j) * 68 + x0];
                    acc[j][0] += wvv * f.x;
                    acc[j][1] += wvv * f.y;
                    acc[j][2] += wvv * f.z;
                    acc[j][3] += wvv * f.w;
                }
            }
#pragma unroll
            for (int j = 0; j < 4; j++) {
                ushort4 o;
                o.x = f2bf(acc[j][0]);
                o.y = f2bf(acc[j][1]);
                o.z = f2bf(acc[j][2]);
                o.w = f2bf(acc[j][3]);
                *(ushort4*)&outp0[(ybase + 4 * s + j) * 64 + x0] = o;
            }
        }
        __syncthreads();
    }
#undef LOADROW
}

// ---------------- K4: partial vk[17][16] per (h,bb,ns) ----------------
__global__ __launch_bounds__(256) void k_vk(const u16* __restrict__ qkvb,
                                            const u16* __restrict__ aggb,
                                            float* __restrict__ gpart) {
    // grid (32 h, NBC bb, 8 ns); block covers 512 cols
    const int h = blockIdx.x, bb = blockIdx.y, ns = blockIdx.z;
    const int tid = threadIdx.x;
    const u16* src = (h < 16) ? qkvb + ((size_t)bb * 768 + h * 48) * 4096
                              : aggb + ((size_t)bb * 768 + (h - 16) * 48) * 4096;
    __shared__ float part[16 * 16 * 17];
    const int e = tid & 15, jg = tid >> 4;
    const int c0 = ns * 512 + jg * 32;
    const u16* kr = src + (size_t)(16 + e) * 4096 + c0;
    const u16* vr = src + (size_t)32 * 4096 + c0;
    float a[17];
#pragma unroll
    for (int d = 0; d < 17; d++) a[d] = 0.f;
#pragma unroll
    for (int i = 0; i < 8; i++) {
        float4 kv = ld4bf(kr + i * 4);
        kv.x = fmaxf(kv.x, 0.f);
        kv.y = fmaxf(kv.y, 0.f);
        kv.z = fmaxf(kv.z, 0.f);
        kv.w = fmaxf(kv.w, 0.f);
#pragma unroll
        for (int d = 0; d < 16; d++) {
            float4 vv = ld4bf(vr + (size_t)d * 4096 + i * 4);
            a[d] += vv.x * kv.x + vv.y * kv.y + vv.z * kv.z + vv.w * kv.w;
        }
        a[16] += kv.x + kv.y + kv.z + kv.w;
    }
#pragma unroll
    for (int d = 0; d < 17; d++) part[(jg * 16 + e) * 17 + d] = a[d];
    __syncthreads();
    for (int idx = tid; idx < 272; idx += 256) {
        int e2 = idx & 15, d2 = idx >> 4;
        float s = 0.f;
#pragma unroll
        for (int j = 0; j < 16; j++) s += part[(j * 16 + e2) * 17 + d2];
        gpart[(((size_t)h * NBC + bb) * 8 + ns) * 272 + idx] = s;
    }
}

// ---------------- K5: reduce partials + attention pass 2 ----------------
__global__ __launch_bounds__(256) void k_att2(const u16* __restrict__ qkvb,
                                              const u16* __restrict__ aggb,
                                              const float* __restrict__ gpart,
                                              u16* __restrict__ attt) {
    // grid (32 h, NBC bb, 8 ns); thread handles 2 cols
    const int h = blockIdx.x, bb = blockIdx.y, ns = blockIdx.z;
    const int tid = threadIdx.x;
    const u16* src = (h < 16) ? qkvb + ((size_t)bb * 768 + h * 48) * 4096
                              : aggb + ((size_t)bb * 768 + (h - 16) * 48) * 4096;
    __shared__ float vks[17][16];
    for (int idx = tid; idx < 272; idx += 256) {
        float s = 0.f;
#pragma unroll
        for (int k = 0; k < 8; k++)
            s += gpart[(((size_t)h * NBC + bb) * 8 + k) * 272 + idx];
        vks[idx >> 4][idx & 15] = s;
    }
    __syncthreads();

    const int n = ns * 512 + tid * 2;
    float2 q2[16];
#pragma unroll
    for (int e = 0; e < 16; e++) {
        ushort2 u = *(const ushort2*)(src + (size_t)e * 4096 + n);
        q2[e] = make_float2(fmaxf(bf2f(u.x), 0.f), fmaxf(bf2f(u.y), 0.f));
    }
    float dx = 0.f, dy = 0.f;
#pragma unroll
    for (int e = 0; e < 16; e++) {
        float w = vks[16][e];
        dx += w * q2[e].x;
        dy += w * q2[e].y;
    }
    float rx = 1.f / fmaxf(dx, 1e-15f);
    float ry = 1.f / fmaxf(dy, 1e-15f);
    us8 o0a, o0b, o1a, o1b;
#pragma unroll
    for (int d = 0; d < 16; d++) {
        float ox = 0.f, oy = 0.f;
#pragma unroll
        for (int e = 0; e < 16; e++) {
            float w = vks[d][e];
            ox += w * q2[e].x;
            oy += w * q2[e].y;
        }
        u16 bx = f2bf(ox * rx), by = f2bf(oy * ry);
        if (d < 8) { o0a[d] = bx; o1a[d] = by; }
        else       { o0b[d - 8] = bx; o1b[d - 8] = by; }
    }
    u16* op = attt + ((size_t)bb * 4096 + n) * 512 + h * 16;
    *(us8*)op = o0a;
    *(us8*)(op + 8) = o0b;
    *(us8*)(op + 512) = o1a;
    *(us8*)(op + 520) = o1b;
}

// ---------------- K6: proj GEMM (256x512 @ 512xN) + BN ----------------
__global__ __launch_bounds__(256) void k_proj_mm(const u16* __restrict__ attt,
                                                 const u16* __restrict__ wpb,
                                                 const float* __restrict__ gamma,
                                                 const float* __restrict__ beta,
                                                 const float* __restrict__ mean,
                                                 const float* __restrict__ var,
                                                 float* __restrict__ out, int b0) {
    const int bid = blockIdx.x;
    const int mt = bid & 1, nt = bid >> 1;
    const int m0 = mt * 128;
    const int cg = nt * 128;
    const int bb = cg >> 12, p0 = cg & 4095;
    const int tid = threadIdx.x, lane = tid & 63, w = tid >> 6;
    const int wm = w >> 1, wn = w & 1;
    const u16* aptr = attt + ((size_t)bb * 4096 + p0 + wn * 64 + (lane & 15)) * 512 + (lane >> 4) * 8;
    const u16* bptr = wpb + (size_t)(m0 + wm * 64 + (lane & 15)) * 512 + (lane >> 4) * 8;

    f32x4 acc[4][4] = {};
#pragma unroll
    for (int ks = 0; ks < 16; ks++) {
        short8v af[4], bf[4];
#pragma unroll
        for (int i = 0; i < 4; i++) {
            af[i] = *(const short8v*)(aptr + (size_t)i * 16 * 512 + ks * 32);
            bf[i] = *(const short8v*)(bptr + (size_t)i * 16 * 512 + ks * 32);
        }
#pragma unroll
        for (int nf = 0; nf < 4; nf++)
#pragma unroll
            for (int mf = 0; mf < 4; mf++)
                acc[nf][mf] = __builtin_amdgcn_mfma_f32_16x16x32_bf16(af[nf], bf[mf], acc[nf][mf], 0, 0, 0);
    }
    const int mbase = m0 + wm * 64 + (lane & 15);
    const int nbase = p0 + wn * 64 + (lane >> 4) * 4;
    float ivv[4], bsv[4];
#pragma unroll
    for (int mf = 0; mf < 4; mf++) {
        int m = mbase + mf * 16;
        float iv = gamma[m] / sqrtf(var[m] + 1e-5f);
        ivv[mf] = iv;
        bsv[mf] = beta[m] - mean[m] * iv;
    }
#pragma unroll
    for (int nf = 0; nf < 4; nf++)
#pragma unroll
        for (int mf = 0; mf < 4; mf++) {
            float4 v;
            v.x = acc[nf][mf][0] * ivv[mf] + bsv[mf];
            v.y = acc[nf][mf][1] * ivv[mf] + bsv[mf];
            v.z = acc[nf][mf][2] * ivv[mf] + bsv[mf];
            v.w = acc[nf][mf][3] * ivv[mf] + bsv[mf];
            *(float4*)(out + ((size_t)(b0 + bb) * 256 + mbase + mf * 16) * 4096 + nbase + nf * 16) = v;
        }
}

extern "C" void kernel_launch(void* const* d_in, const int* in_sizes, int n_in,
                              void* d_out, int out_size, void* d_ws, size_t ws_size,
                              hipStream_t stream) {
    const float* x = (const float*)d_in[0];
    const float* wq = (const float*)d_in[1];
    const float* wdw = (const float*)d_in[2];
    const float* wpw = (const float*)d_in[3];
    const float* wp = (const float*)d_in[4];
    const float* gamma = (const float*)d_in[5];
    const float* beta = (const float*)d_in[6];
    const float* mean = (const float*)d_in[7];
    const float* var = (const float*)d_in[8];
    float* out = (float*)d_out;

    u16* ws = (u16*)d_ws;
    u16* xbt = ws;                                      // NBC*4096*256
    u16* qkvb = xbt + (size_t)NBC * 4096 * 256;         // NBC*768*4096
    u16* aggb = qkvb + (size_t)NBC * 768 * 4096;        // NBC*768*4096
    u16* attt = aggb + (size_t)NBC * 768 * 4096;        // NBC*4096*512
    u16* wqb = attt + (size_t)NBC * 4096 * 512;         // 768*256
    u16* wpb = wqb + 768 * 256;                         // 256*512
    float* gpart = (float*)(wpb + 256 * 512);           // 32*NBC*8*272 fp32

    k_cvt_w<<<768, 256, 0, stream>>>(wq, wp, wqb, wpb);
    for (int chunk = 0; chunk < 2; ++chunk) {
        int b0 = chunk * NBC;
        k_tr_x<<<dim3(64, 4, NBC), 256, 0, stream>>>(x, xbt, b0);
        k_qkv_mm<<<1536, 256, 0, stream>>>(xbt, wqb, qkvb);
        k_dwpw<<<dim3(2, 48, NBC), 256, 0, stream>>>(qkvb, wdw, wpw, aggb);
        k_vk<<<dim3(32, NBC, 8), 256, 0, stream>>>(qkvb, aggb, gpart);
        k_att2<<<dim3(32, NBC, 8), 256, 0, stream>>>(qkvb, aggb, gpart, attt);
        k_proj_mm<<<512, 256, 0, stream>>>(attt, wpb, gamma, beta, mean, var, out, b0);
    }
}

// Round 7
// 593.548 us; speedup vs baseline: 1.0007x; 1.0007x over previous
//
#include <hip/hip_runtime.h>
#include <math.h>

// LiteMLA bf16/MFMA pipeline. 2 chunks x 8 batches.
// K0 k_cvt_w : wq, wp fp32 -> bf16 (once)
// K1 k_tr_x  : x[c][n] fp32 -> xb_t[n][c] bf16
// K2 k_qkv_mm: qkv GEMM via mfma_f32_16x16x32_bf16, no-LDS direct frag loads
// K3 k_dwpw  : fused depthwise 5x5 + grouped pointwise, bf16 io, fp32 math
//              v4: v3 marching blocks, but rows[][] indexed ONLY with
//              compile-time constants (no pointer into array -> stays in VGPRs)
// K4 k_vk   : partial vk[17][16] per (h,bb,ns) -> ws fp32   (2048 blocks)
// K5 k_att2 : reduce partials + pass2, writes att_t[n][512] (2048 blocks)
// K6 k_proj_mm: proj GEMM + BN affine, fp32 out

#define NBC 8

typedef unsigned short u16;
typedef __attribute__((ext_vector_type(8))) short short8v;
typedef __attribute__((ext_vector_type(8))) unsigned short us8;
typedef __attribute__((ext_vector_type(4))) float f32x4;

__device__ __forceinline__ u16 f2bf(float f) {
    union { float f; unsigned u; } v; v.f = f;
    unsigned r = v.u + 0x7fffu + ((v.u >> 16) & 1u);
    return (u16)(r >> 16);
}
__device__ __forceinline__ float bf2f(u16 u) {
    union { unsigned u; float f; } v; v.u = ((unsigned)u) << 16;
    return v.f;
}
__device__ __forceinline__ float4 ld4bf(const u16* p) {
    ushort4 u = *(const ushort4*)p;
    return make_float4(bf2f(u.x), bf2f(u.y), bf2f(u.z), bf2f(u.w));
}

// ---------------- K0: weight conversion ----------------
__global__ __launch_bounds__(256) void k_cvt_w(const float* __restrict__ wq,
                                               const float* __restrict__ wp,
                                               u16* __restrict__ wqb, u16* __restrict__ wpb) {
    int i = blockIdx.x * 256 + threadIdx.x;
    if (i < 768 * 256) wqb[i] = f2bf(wq[i]);
    if (i < 256 * 512) wpb[i] = f2bf(wp[i]);
}

// ---------------- K1: transpose x -> xb_t bf16 ----------------
__global__ __launch_bounds__(256) void k_tr_x(const float* __restrict__ x,
                                              u16* __restrict__ xbt, int b0) {
    __shared__ u16 t[64][72];
    const int nt = blockIdx.x, ct = blockIdx.y, bb = blockIdx.z;
    const int tid = threadIdx.x;
    const float* xp = x + ((size_t)(b0 + bb) * 256 + ct * 64) * 4096 + nt * 64;
    {
        int cr = tid >> 2, q = tid & 3;
#pragma unroll
        for (int j = 0; j < 4; j++) {
            float4 v = *(const float4*)&xp[(size_t)cr * 4096 + q * 16 + j * 4];
            ushort4 o;
            o.x = f2bf(v.x); o.y = f2bf(v.y); o.z = f2bf(v.z); o.w = f2bf(v.w);
            *(ushort4*)&t[cr][q * 16 + j * 4] = o;
        }
    }
    __syncthreads();
    {
        int nr = tid >> 2, co = (tid & 3) * 16;
        u16* op = xbt + ((size_t)bb * 4096 + nt * 64 + nr) * 256 + ct * 64 + co;
        us8 o0, o1;
#pragma unroll
        for (int j = 0; j < 8; j++) { o0[j] = t[co + j][nr]; o1[j] = t[co + 8 + j][nr]; }
        *(us8*)op = o0;
        *(us8*)(op + 8) = o1;
    }
}

// ---------------- K2: qkv GEMM (768x256 @ 256xN) ----------------
__global__ __launch_bounds__(256) void k_qkv_mm(const u16* __restrict__ xbt,
                                                const u16* __restrict__ wqb,
                                                u16* __restrict__ qkvb) {
    const int bid = blockIdx.x;
    const int mt = bid % 6, nt = bid / 6;
    const int m0 = mt * 128;
    const int cg = nt * 128;
    const int bb = cg >> 12, p0 = cg & 4095;
    const int tid = threadIdx.x, lane = tid & 63, w = tid >> 6;
    const int wm = w >> 1, wn = w & 1;
    const u16* aptr = xbt + ((size_t)bb * 4096 + p0 + wn * 64 + (lane & 15)) * 256 + (lane >> 4) * 8;
    const u16* bptr = wqb + (size_t)(m0 + wm * 64 + (lane & 15)) * 256 + (lane >> 4) * 8;

    f32x4 acc[4][4] = {};
#pragma unroll
    for (int ks = 0; ks < 8; ks++) {
        short8v af[4], bf[4];
#pragma unroll
        for (int i = 0; i < 4; i++) {
            af[i] = *(const short8v*)(aptr + (size_t)i * 16 * 256 + ks * 32);
            bf[i] = *(const short8v*)(bptr + (size_t)i * 16 * 256 + ks * 32);
        }
#pragma unroll
        for (int nf = 0; nf < 4; nf++)
#pragma unroll
            for (int mf = 0; mf < 4; mf++)
                acc[nf][mf] = __builtin_amdgcn_mfma_f32_16x16x32_bf16(af[nf], bf[mf], acc[nf][mf], 0, 0, 0);
    }
    const int mbase = m0 + wm * 64 + (lane & 15);
    const int nbase = p0 + wn * 64 + (lane >> 4) * 4;
#pragma unroll
    for (int nf = 0; nf < 4; nf++)
#pragma unroll
        for (int mf = 0; mf < 4; mf++) {
            int c = mbase + mf * 16;
            int nn = nbase + nf * 16;
            ushort4 o;
            o.x = f2bf(acc[nf][mf][0]);
            o.y = f2bf(acc[nf][mf][1]);
            o.z = f2bf(acc[nf][mf][2]);
            o.w = f2bf(acc[nf][mf][3]);
            *(ushort4*)(qkvb + ((size_t)bb * 768 + c) * 4096 + nn) = o;
        }
}

// ---------------- K3: fused depthwise 5x5 + grouped pointwise (v4) ----------------
__global__ __launch_bounds__(256, 3) void k_dwpw(const u16* __restrict__ qkvb,
                                                 const float* __restrict__ wdw,
                                                 const float* __restrict__ wpw,
                                                 u16* __restrict__ aggb) {
    // grid: (ys 2, g 48, bb NBC) = 768 blocks; each marches 32 rows in 8 steps of 4
    __shared__ float dwt[16 * 4 * 68];  // [ic][ry][x], row stride 68
    const int tid = threadIdx.x;
    const int ys = blockIdx.x, g = blockIdx.y, bb = blockIdx.z;
    const int cl = tid >> 4, xq = tid & 15;
    const int c = g * 16 + cl;
    const int x0 = xq * 4;
    const int ybase = ys * 32;
    const u16* in = qkvb + ((size_t)bb * 768 + c) * 4096;
    u16* outp0 = aggb + ((size_t)bb * 768 + c) * 4096;  // oc == cl in pw phase

    float w[5][5];
#pragma unroll
    for (int dy = 0; dy < 5; dy++)
#pragma unroll
        for (int dx = 0; dx < 5; dx++) w[dy][dx] = wdw[c * 25 + dy * 5 + dx];
    float wv[16];
#pragma unroll
    for (int ic = 0; ic < 16; ic++) wv[ic] = wpw[(size_t)c * 16 + ic];

    float rows[8][8];  // rotating window; row yy lives in slot (yy+2)&7 (ybase%8==0)
                       // all accesses use compile-time-constant indices -> VGPRs

#define LOADROW(YY, SLOT)                                                     \
    {                                                                         \
        int yy_ = (YY);                                                       \
        if (yy_ < 0 || yy_ > 63) {                                            \
            _Pragma("unroll") for (int j_ = 0; j_ < 8; j_++) rows[SLOT][j_] = 0.f; \
        } else {                                                              \
            const u16* rp_ = in + yy_ * 64;                                   \
            float4 v0_ = (x0 >= 4) ? ld4bf(rp_ + x0 - 4) : make_float4(0, 0, 0, 0); \
            float4 v1_ = ld4bf(rp_ + x0);                                     \
            float4 v2_ = (x0 + 4 < 64) ? ld4bf(rp_ + x0 + 4) : make_float4(0, 0, 0, 0); \
            rows[SLOT][0] = v0_.z; rows[SLOT][1] = v0_.w;                     \
            rows[SLOT][2] = v1_.x; rows[SLOT][3] = v1_.y;                     \
            rows[SLOT][4] = v1_.z; rows[SLOT][5] = v1_.w;                     \
            rows[SLOT][6] = v2_.x; rows[SLOT][7] = v2_.y;                     \
        }                                                                     \
    }

    // init: rows ybase-2 .. ybase+5 -> slots 0..7
#pragma unroll
    for (int i = 0; i < 8; i++) LOADROW(ybase - 2 + i, i)

#pragma unroll
    for (int s = 0; s < 8; s++) {
        // ---- depthwise: output rows ybase+4s .. +3; slot index is constexpr ----
#pragma unroll
        for (int ry = 0; ry < 4; ry++) {
            float o0 = 0.f, o1 = 0.f, o2 = 0.f, o3 = 0.f;
#pragma unroll
            for (int dy = 0; dy < 5; dy++) {
#pragma unroll
                for (int dx = 0; dx < 5; dx++) {
                    float wvv = w[dy][dx];
                    o0 += rows[(4 * s + ry + dy) & 7][0 + dx] * wvv;
                    o1 += rows[(4 * s + ry + dy) & 7][1 + dx] * wvv;
                    o2 += rows[(4 * s + ry + dy) & 7][2 + dx] * wvv;
                    o3 += rows[(4 * s + ry + dy) & 7][3 + dx] * wvv;
                }
            }
            float4 ov = make_float4(o0, o1, o2, o3);
            *(float4*)&dwt[(cl * 4 + ry) * 68 + x0] = ov;
        }
        // ---- prefetch next 4 rows into the 4 just-freed slots ----
        if (s < 7) {
#pragma unroll
            for (int i = 0; i < 4; i++) LOADROW(ybase + 4 * s + 6 + i, (4 * s + i) & 7)
        }
        __syncthreads();
        // ---- grouped pointwise: thread = (oc=cl, 4px) ----
        {
            float acc[4][4];
#pragma unroll
            for (int j = 0; j < 4; j++)
#pragma unroll
                for (int p = 0; p < 4; p++) acc[j][p] = 0.f;
#pragma unroll
            for (int ic = 0; ic < 16; ic++) {
                float wvv = wv[ic];
#pragma unroll
                for (int j = 0; j < 4; j++) {
                    float4 f = *(const float4*)&dwt[(ic * 4 + j) * 68 + x0];
                    acc[j][0] += wvv * f.x;
                    acc[j][1] += wvv * f.y;
                    acc[j][2] += wvv * f.z;
                    acc[j][3] += wvv * f.w;
                }
            }
#pragma unroll
            for (int j = 0; j < 4; j++) {
                ushort4 o;
                o.x = f2bf(acc[j][0]);
                o.y = f2bf(acc[j][1]);
                o.z = f2bf(acc[j][2]);
                o.w = f2bf(acc[j][3]);
                *(ushort4*)&outp0[(ybase + 4 * s + j) * 64 + x0] = o;
            }
        }
        __syncthreads();
    }
#undef LOADROW
}

// ---------------- K4: partial vk[17][16] per (h,bb,ns) ----------------
__global__ __launch_bounds__(256) void k_vk(const u16* __restrict__ qkvb,
                                            const u16* __restrict__ aggb,
                                            float* __restrict__ gpart) {
    // grid (32 h, NBC bb, 8 ns); block covers 512 cols
    const int h = blockIdx.x, bb = blockIdx.y, ns = blockIdx.z;
    const int tid = threadIdx.x;
    const u16* src = (h < 16) ? qkvb + ((size_t)bb * 768 + h * 48) * 4096
                              : aggb + ((size_t)bb * 768 + (h - 16) * 48) * 4096;
    __shared__ float part[16 * 16 * 17];
    const int e = tid & 15, jg = tid >> 4;
    const int c0 = ns * 512 + jg * 32;
    const u16* kr = src + (size_t)(16 + e) * 4096 + c0;
    const u16* vr = src + (size_t)32 * 4096 + c0;
    float a[17];
#pragma unroll
    for (int d = 0; d < 17; d++) a[d] = 0.f;
#pragma unroll
    for (int i = 0; i < 8; i++) {
        float4 kv = ld4bf(kr + i * 4);
        kv.x = fmaxf(kv.x, 0.f);
        kv.y = fmaxf(kv.y, 0.f);
        kv.z = fmaxf(kv.z, 0.f);
        kv.w = fmaxf(kv.w, 0.f);
#pragma unroll
        for (int d = 0; d < 16; d++) {
            float4 vv = ld4bf(vr + (size_t)d * 4096 + i * 4);
            a[d] += vv.x * kv.x + vv.y * kv.y + vv.z * kv.z + vv.w * kv.w;
        }
        a[16] += kv.x + kv.y + kv.z + kv.w;
    }
#pragma unroll
    for (int d = 0; d < 17; d++) part[(jg * 16 + e) * 17 + d] = a[d];
    __syncthreads();
    for (int idx = tid; idx < 272; idx += 256) {
        int e2 = idx & 15, d2 = idx >> 4;
        float s = 0.f;
#pragma unroll
        for (int j = 0; j < 16; j++) s += part[(j * 16 + e2) * 17 + d2];
        gpart[(((size_t)h * NBC + bb) * 8 + ns) * 272 + idx] = s;
    }
}

// ---------------- K5: reduce partials + attention pass 2 ----------------
__global__ __launch_bounds__(256) void k_att2(const u16* __restrict__ qkvb,
                                              const u16* __restrict__ aggb,
                                              const float* __restrict__ gpart,
                                              u16* __restrict__ attt) {
    // grid (32 h, NBC bb, 8 ns); thread handles 2 cols
    const int h = blockIdx.x, bb = blockIdx.y, ns = blockIdx.z;
    const int tid = threadIdx.x;
    const u16* src = (h < 16) ? qkvb + ((size_t)bb * 768 + h * 48) * 4096
                              : aggb + ((size_t)bb * 768 + (h - 16) * 48) * 4096;
    __shared__ float vks[17][16];
    for (int idx = tid; idx < 272; idx += 256) {
        float s = 0.f;
#pragma unroll
        for (int k = 0; k < 8; k++)
            s += gpart[(((size_t)h * NBC + bb) * 8 + k) * 272 + idx];
        vks[idx >> 4][idx & 15] = s;
    }
    __syncthreads();

    const int n = ns * 512 + tid * 2;
    float2 q2[16];
#pragma unroll
    for (int e = 0; e < 16; e++) {
        ushort2 u = *(const ushort2*)(src + (size_t)e * 4096 + n);
        q2[e] = make_float2(fmaxf(bf2f(u.x), 0.f), fmaxf(bf2f(u.y), 0.f));
    }
    float dx = 0.f, dy = 0.f;
#pragma unroll
    for (int e = 0; e < 16; e++) {
        float w = vks[16][e];
        dx += w * q2[e].x;
        dy += w * q2[e].y;
    }
    float rx = 1.f / fmaxf(dx, 1e-15f);
    float ry = 1.f / fmaxf(dy, 1e-15f);
    us8 o0a, o0b, o1a, o1b;
#pragma unroll
    for (int d = 0; d < 16; d++) {
        float ox = 0.f, oy = 0.f;
#pragma unroll
        for (int e = 0; e < 16; e++) {
            float w = vks[d][e];
            ox += w * q2[e].x;
            oy += w * q2[e].y;
        }
        u16 bx = f2bf(ox * rx), by = f2bf(oy * ry);
        if (d < 8) { o0a[d] = bx; o1a[d] = by; }
        else       { o0b[d - 8] = bx; o1b[d - 8] = by; }
    }
    u16* op = attt + ((size_t)bb * 4096 + n) * 512 + h * 16;
    *(us8*)op = o0a;
    *(us8*)(op + 8) = o0b;
    *(us8*)(op + 512) = o1a;
    *(us8*)(op + 520) = o1b;
}

// ---------------- K6: proj GEMM (256x512 @ 512xN) + BN ----------------
__global__ __launch_bounds__(256) void k_proj_mm(const u16* __restrict__ attt,
                                                 const u16* __restrict__ wpb,
                                                 const float* __restrict__ gamma,
                                                 const float* __restrict__ beta,
                                                 const float* __restrict__ mean,
                                                 const float* __restrict__ var,
                                                 float* __restrict__ out, int b0) {
    const int bid = blockIdx.x;
    const int mt = bid & 1, nt = bid >> 1;
    const int m0 = mt * 128;
    const int cg = nt * 128;
    const int bb = cg >> 12, p0 = cg & 4095;
    const int tid = threadIdx.x, lane = tid & 63, w = tid >> 6;
    const int wm = w >> 1, wn = w & 1;
    const u16* aptr = attt + ((size_t)bb * 4096 + p0 + wn * 64 + (lane & 15)) * 512 + (lane >> 4) * 8;
    const u16* bptr = wpb + (size_t)(m0 + wm * 64 + (lane & 15)) * 512 + (lane >> 4) * 8;

    f32x4 acc[4][4] = {};
#pragma unroll
    for (int ks = 0; ks < 16; ks++) {
        short8v af[4], bf[4];
#pragma unroll
        for (int i = 0; i < 4; i++) {
            af[i] = *(const short8v*)(aptr + (size_t)i * 16 * 512 + ks * 32);
            bf[i] = *(const short8v*)(bptr + (size_t)i * 16 * 512 + ks * 32);
        }
#pragma unroll
        for (int nf = 0; nf < 4; nf++)
#pragma unroll
            for (int mf = 0; mf < 4; mf++)
                acc[nf][mf] = __builtin_amdgcn_mfma_f32_16x16x32_bf16(af[nf], bf[mf], acc[nf][mf], 0, 0, 0);
    }
    const int mbase = m0 + wm * 64 + (lane & 15);
    const int nbase = p0 + wn * 64 + (lane >> 4) * 4;
    float ivv[4], bsv[4];
#pragma unroll
    for (int mf = 0; mf < 4; mf++) {
        int m = mbase + mf * 16;
        float iv = gamma[m] / sqrtf(var[m] + 1e-5f);
        ivv[mf] = iv;
        bsv[mf] = beta[m] - mean[m] * iv;
    }
#pragma unroll
    for (int nf = 0; nf < 4; nf++)
#pragma unroll
        for (int mf = 0; mf < 4; mf++) {
            float4 v;
            v.x = acc[nf][mf][0] * ivv[mf] + bsv[mf];
            v.y = acc[nf][mf][1] * ivv[mf] + bsv[mf];
            v.z = acc[nf][mf][2] * ivv[mf] + bsv[mf];
            v.w = acc[nf][mf][3] * ivv[mf] + bsv[mf];
            *(float4*)(out + ((size_t)(b0 + bb) * 256 + mbase + mf * 16) * 4096 + nbase + nf * 16) = v;
        }
}

extern "C" void kernel_launch(void* const* d_in, const int* in_sizes, int n_in,
                              void* d_out, int out_size, void* d_ws, size_t ws_size,
                              hipStream_t stream) {
    const float* x = (const float*)d_in[0];
    const float* wq = (const float*)d_in[1];
    const float* wdw = (const float*)d_in[2];
    const float* wpw = (const float*)d_in[3];
    const float* wp = (const float*)d_in[4];
    const float* gamma = (const float*)d_in[5];
    const float* beta = (const float*)d_in[6];
    const float* mean = (const float*)d_in[7];
    const float* var = (const float*)d_in[8];
    float* out = (float*)d_out;

    u16* ws = (u16*)d_ws;
    u16* xbt = ws;                                      // NBC*4096*256
    u16* qkvb = xbt + (size_t)NBC * 4096 * 256;         // NBC*768*4096
    u16* aggb = qkvb + (size_t)NBC * 768 * 4096;        // NBC*768*4096
    u16* attt = aggb + (size_t)NBC * 768 * 4096;        // NBC*4096*512
    u16* wqb = attt + (size_t)NBC * 4096 * 512;         // 768*256
    u16* wpb = wqb + 768 * 256;                         // 256*512
    float* gpart = (float*)(wpb + 256 * 512);           // 32*NBC*8*272 fp32

    k_cvt_w<<<768, 256, 0, stream>>>(wq, wp, wqb, wpb);
    for (int chunk = 0; chunk < 2; ++chunk) {
        int b0 = chunk * NBC;
        k_tr_x<<<dim3(64, 4, NBC), 256, 0, stream>>>(x, xbt, b0);
        k_qkv_mm<<<1536, 256, 0, stream>>>(xbt, wqb, qkvb);
        k_dwpw<<<dim3(2, 48, NBC), 256, 0, stream>>>(qkvb, wdw, wpw, aggb);
        k_vk<<<dim3(32, NBC, 8), 256, 0, stream>>>(qkvb, aggb, gpart);
        k_att2<<<dim3(32, NBC, 8), 256, 0, stream>>>(qkvb, aggb, gpart, attt);
        k_proj_mm<<<512, 256, 0, stream>>>(attt, wpb, gamma, beta, mean, var, out, b0);
    }
}